// Round 11
// baseline (77.643 us; speedup 1.0000x reference)
//
#include <hip/hip_runtime.h>
#include <hip/hip_bf16.h>

// Problem constants
constexpr int   D      = 512;
constexpr float ALPHA  = 1.0f;
constexpr float EPS    = 1e-9f;
constexpr float INV_CNT = 1.0f / (32.0f * 128.0f * 128.0f);  // 1/524288

// ws layout (bytes)
constexpr size_t NRM_OFF  = 0;            // 8192*512*2  = 8388608 (bf16)
constexpr size_t PWS_OFF  = 8388608;      // 512*16*256*4 = 8388608 (f32 P panels)
constexpr size_t PART_OFF = 16777216;     // 2048*4
constexpr size_t CNT_OFF  = 16785408;     // int counter (memset to 0 each call)

typedef short bf16x8 __attribute__((ext_vector_type(8)));
typedef float f32x4  __attribute__((ext_vector_type(4)));

// round-to-nearest-even f32 -> bf16 bits
__device__ __forceinline__ short f2bf(float f) {
    unsigned u = __builtin_bit_cast(unsigned, f);
    unsigned r = (u + 0x7FFFu + ((u >> 16) & 1u)) >> 16;
    return (short)r;
}

// async global->LDS, 16B per lane; dest = uniform base + lane*16 (HW rule)
typedef __attribute__((address_space(3))) char lds_char;
typedef const __attribute__((address_space(1))) char g_char;
__device__ __forceinline__ void glds16(const void* g, void* l) {
    __builtin_amdgcn_global_load_lds((g_char*)g, (lds_char*)l, 16, 0, 0);
}

// ---------------------------------------------------------------------------
// K1: row-normalize fp32 -> bf16. One wave per row. 2048 blocks x 256.
__global__ __launch_bounds__(256) void k_normalize(const float* __restrict__ in,
                                                   short* __restrict__ out) {
    const int wid  = threadIdx.x >> 6;
    const int lane = threadIdx.x & 63;
    const int r    = blockIdx.x * 4 + wid;
    const float4* src = (const float4*)(in + (size_t)r * D);
    float4 x0 = src[2 * lane];
    float4 x1 = src[2 * lane + 1];
    float ss = x0.x*x0.x + x0.y*x0.y + x0.z*x0.z + x0.w*x0.w
             + x1.x*x1.x + x1.y*x1.y + x1.z*x1.z + x1.w*x1.w;
    #pragma unroll
    for (int o = 32; o > 0; o >>= 1) ss += __shfl_xor(ss, o, 64);
    const float inv = rsqrtf(ss);
    bf16x8 v;
    v[0] = f2bf(x0.x * inv); v[1] = f2bf(x0.y * inv);
    v[2] = f2bf(x0.z * inv); v[3] = f2bf(x0.w * inv);
    v[4] = f2bf(x1.x * inv); v[5] = f2bf(x1.y * inv);
    v[6] = f2bf(x1.z * inv); v[7] = f2bf(x1.w * inv);
    ((bf16x8*)(out + (size_t)r * D))[lane] = v;
}

// ---------------------------------------------------------------------------
// K2: gram panels. 512 blocks x 256 thr (4 waves), 2 independent blocks/CU.
// Block = (b, chunk, half): A = 16 rows (t-chunk if half=0 else c-chunk),
// B = all 256 batch rows. Wave w owns B-cols [w*64,+64), staging its own
// 64 rows x 32k slice (4 KB) via glds triple-buffer, distance-2 prefetch,
// vmcnt(5) steady state (5 VMEM ops per step: 1 A + 4 B-glds).
// P panel written f32 to ws: pws[blk][16][256].
//   half=0: P[:,0:128]=t.t (pd), P[:,128:256]=t.c (pn)
//   half=1: P[:,128:256]=c.c (pd), P[:,0:128]=c.t (pn)
__global__ __launch_bounds__(256, 2) void k_gram(const short* __restrict__ nrm,
                                                 float* __restrict__ pws) {
    __shared__ __align__(16) char smem[49152];    // 3 bufs x 16 KB

    const int p     = blockIdx.x;
    const int slot  = p >> 3;
    const int b     = (p & 7) * 4 + (slot & 3);   // XCD-bijective: 4 batches/XCD
    const int rem   = slot >> 2;                  // 0..15
    const int chunk = rem & 7;
    const int half  = rem >> 3;
    const int w     = threadIdx.x >> 6;
    const int lane  = threadIdx.x & 63;
    const int fr    = lane & 15;
    const int kg    = lane >> 4;

    const short* base = nrm + (size_t)b * 256 * D;
    const int Arow0 = half * 128 + chunk * 16;
    const short* gA = base + (size_t)(Arow0 + fr) * D + 8 * kg;
    const int brow0 = w * 64;                     // this wave's 64 B-rows

    // B staging: slice ks -> buffer bi (wave-private 4 KB region)
    auto stageB = [&](int ks, int bi) {
        #pragma unroll
        for (int t = 0; t < 4; t++) {
            const int sl  = t * 64 + lane;        // 16B chunk slot (0..255)
            const int row = sl >> 2;              // 0..63
            const int pp  = sl & 3;               // stored position
            const int gch = pp ^ (row & 3);       // pre-swizzled source chunk
            const short* src = base + (size_t)(brow0 + row) * D + ks * 32 + gch * 8;
            glds16(src, &smem[bi * 16384 + w * 4096 + t * 1024]); // +lane*16
        }
    };

    f32x4 acc0 = {0.f,0.f,0.f,0.f}, acc1 = {0.f,0.f,0.f,0.f};
    f32x4 acc2 = {0.f,0.f,0.f,0.f}, acc3 = {0.f,0.f,0.f,0.f};
    bf16x8 aA[3];                                 // rotating A buffers

    // prologue: [A(0),B(0)x4, A(1),B(1)x4] = 10 ops; wait until group 0 done
    aA[0] = *(const bf16x8*)(gA + 0);
    stageB(0, 0);
    aA[1] = *(const bf16x8*)(gA + 32);
    stageB(1, 1);
    asm volatile("s_waitcnt vmcnt(5)" ::: "memory");
    __builtin_amdgcn_sched_barrier(0);

    const int pb = (kg ^ (fr & 3)) * 16;          // swizzled read position
    #pragma unroll
    for (int s = 0; s < 16; s++) {
        if (s < 14) {
            aA[(s + 2) % 3] = *(const bf16x8*)(gA + (s + 2) * 32);
            stageB(s + 2, (s + 2) % 3);
        }
        const int bo = (s % 3) * 16384 + w * 4096;
        bf16x8 b0 = *(const bf16x8*)&smem[bo + ( 0 + fr) * 64 + pb];
        bf16x8 b1 = *(const bf16x8*)&smem[bo + (16 + fr) * 64 + pb];
        bf16x8 b2 = *(const bf16x8*)&smem[bo + (32 + fr) * 64 + pb];
        bf16x8 b3 = *(const bf16x8*)&smem[bo + (48 + fr) * 64 + pb];
        acc0 = __builtin_amdgcn_mfma_f32_16x16x32_bf16(aA[s % 3], b0, acc0, 0, 0, 0);
        acc1 = __builtin_amdgcn_mfma_f32_16x16x32_bf16(aA[s % 3], b1, acc1, 0, 0, 0);
        acc2 = __builtin_amdgcn_mfma_f32_16x16x32_bf16(aA[s % 3], b2, acc2, 0, 0, 0);
        acc3 = __builtin_amdgcn_mfma_f32_16x16x32_bf16(aA[s % 3], b3, acc3, 0, 0, 0);
        if (s < 14)      { asm volatile("s_waitcnt vmcnt(5)" ::: "memory"); }
        else if (s == 14){ asm volatile("s_waitcnt vmcnt(0)" ::: "memory"); }
        __builtin_amdgcn_sched_barrier(0);
    }

    // C/D layout (m89-verified): lane l, reg q -> row kg*4+q, col fr
    float* Pb = pws + (size_t)p * 4096;
    #pragma unroll
    for (int q = 0; q < 4; q++) {
        const int r = kg * 4 + q;
        Pb[r * 256 + w * 64 +  0 + fr] = acc0[q];
        Pb[r * 256 + w * 64 + 16 + fr] = acc1[q];
        Pb[r * 256 + w * 64 + 32 + fr] = acc2[q];
        Pb[r * 256 + w * 64 + 48 + fr] = acc3[q];
    }
}

// ---------------------------------------------------------------------------
// K3: loss at FULL occupancy. 2048 blocks x 256 thr = 8192 waves, one wave
// per (row of a P panel) = one (b,side,i). 32 waves/CU hides the sort/search
// latency chains that were exposed at 2 waves/SIMD in the fused design.
// Verified sort + prefix + binary-search closed form (rounds 3-10).
// Last block (atomic counter) reduces 2048 partials -> out[0].
__global__ __launch_bounds__(256) void k_loss(const float* __restrict__ pws,
                                              float* __restrict__ part,
                                              int* __restrict__ counter,
                                              float* __restrict__ out) {
    __shared__ float sc[4][260];
    __shared__ float red[4];
    __shared__ int lastflag;

    const int w    = threadIdx.x >> 6;
    const int lane = threadIdx.x & 63;
    const int rg   = blockIdx.x * 4 + w;          // 0..8191
    const int blk  = rg >> 4;                     // gram block id
    const int i    = rg & 15;
    const int half = ((blk >> 3) >> 2) >> 3;      // slot=blk>>3, rem=slot>>2, half=rem>>3
    const int pd_off = half ? 128 : 0;
    const int pn_off = 128 - pd_off;

    const float* Pr = pws + (size_t)blk * 4096 + i * 256;
    const float g0 = Pr[pd_off + lane];
    const float g1 = Pr[pd_off + lane + 64];
    float v0 = Pr[pn_off + lane];
    float v1 = Pr[pn_off + lane + 64];

    // bitonic sort ascending (2 elems/lane)
    #pragma unroll
    for (int kk = 2; kk <= 128; kk <<= 1) {
        if (kk == 128) {
            const float lo = fminf(v0, v1);
            const float hi = fmaxf(v0, v1);
            v0 = lo; v1 = hi;
        }
        #pragma unroll
        for (int j = (kk == 128 ? 32 : (kk >> 1)); j >= 1; j >>= 1) {
            const float p0 = __shfl_xor(v0, j, 64);
            const float p1 = __shfl_xor(v1, j, 64);
            const bool up0 = (lane & kk) == 0;
            const bool up1 = ((lane + 64) & kk) == 0;
            const bool lower = (lane & j) == 0;
            v0 = (up0 == lower) ? fminf(v0, p0) : fmaxf(v0, p0);
            v1 = (up1 == lower) ? fminf(v1, p1) : fmaxf(v1, p1);
        }
    }

    // inclusive prefix scans of the two halves
    float inc0 = v0, inc1 = v1;
    #pragma unroll
    for (int o = 1; o < 64; o <<= 1) {
        const float t0 = __shfl_up(inc0, o, 64);
        const float t1 = __shfl_up(inc1, o, 64);
        if (lane >= o) { inc0 += t0; inc1 += t1; }
    }
    const float tot0  = __shfl(inc0, 63, 64);
    const float total = tot0 + __shfl(inc1, 63, 64);

    // write sorted s[0:128] and exclusive prefix pre[0:129] to wave scratch
    float* prow = sc[w];
    prow[lane]            = v0;
    prow[64 + lane]       = v1;
    prow[130 + 1 + lane]  = inc0;
    prow[130 + 65 + lane] = tot0 + inc1;
    if (lane == 0) prow[130] = 0.f;

    // per-j: rank via guarded binary search, closed-form num/den
    float wacc = 0.f;
    #pragma unroll
    for (int h = 0; h < 2; h++) {
        const float g   = h ? g1 : g0;
        const float tau = g - 0.5f * ALPHA;       // v>0 <=> h_k > tau
        const float a   = ALPHA - 2.f * g;
        int pos = 0;
        #pragma unroll
        for (int st = 128; st > 0; st >>= 1) {
            const int nidx = pos + st;
            const float sv = prow[nidx - 1];
            pos = ((nidx <= 128) && (sv <= tau)) ? nidx : pos;
        }
        const float cnt = (float)(128 - pos);
        const float pre = prow[130 + pos];
        const float num = cnt * a + 2.f * (total - pre);
        wacc += num / (cnt + EPS);
    }

    #pragma unroll
    for (int o = 32; o > 0; o >>= 1) wacc += __shfl_xor(wacc, o, 64);
    if (lane == 0) red[w] = wacc;
    __syncthreads();
    if (threadIdx.x == 0) {
        part[blockIdx.x] = red[0] + red[1] + red[2] + red[3];
        __threadfence();                          // release part[blockIdx.x]
        lastflag = atomicAdd(counter, 1);         // device-scope
    }
    __syncthreads();

    // last block reduces all 2048 partials -> out[0]
    if (lastflag == 2047) {
        __threadfence();                          // acquire
        float s = 0.f;
        #pragma unroll
        for (int k = 0; k < 8; k++) s += part[threadIdx.x + k * 256];
        #pragma unroll
        for (int o = 32; o > 0; o >>= 1) s += __shfl_xor(s, o, 64);
        if (lane == 0) red[w] = s;
        __syncthreads();
        if (threadIdx.x == 0) {
            float t = 0.f;
            #pragma unroll
            for (int k = 0; k < 4; k++) t += red[k];
            out[0] = t * INV_CNT;
        }
    }
}

// ---------------------------------------------------------------------------
extern "C" void kernel_launch(void* const* d_in, const int* in_sizes, int n_in,
                              void* d_out, int out_size, void* d_ws, size_t ws_size,
                              hipStream_t stream) {
    const float* latent = (const float*)d_in[0];
    float* out  = (float*)d_out;
    char*  wsb  = (char*)d_ws;
    short* nrm  = (short*)(wsb + NRM_OFF);
    float* pws  = (float*)(wsb + PWS_OFF);
    float* part = (float*)(wsb + PART_OFF);
    int*   cnt  = (int*)(wsb + CNT_OFF);

    hipMemsetAsync(cnt, 0, sizeof(int), stream);
    hipLaunchKernelGGL(k_normalize, dim3(2048), dim3(256), 0, stream, latent, nrm);
    hipLaunchKernelGGL(k_gram,      dim3(512),  dim3(256), 0, stream, nrm, pws);
    hipLaunchKernelGGL(k_loss,      dim3(2048), dim3(256), 0, stream, pws, part, cnt, out);
}

// Round 12
// 38.399 us; speedup vs baseline: 2.0220x; 2.0220x over previous
//
#include <hip/hip_runtime.h>
#include <hip/hip_bf16.h>

// Problem constants
constexpr int   D      = 512;
constexpr float ALPHA  = 1.0f;
constexpr float EPS    = 1e-9f;
constexpr float INV_CNT = 1.0f / (32.0f * 128.0f * 128.0f);  // 1/524288

// ws layout (bytes)
constexpr size_t NRM_OFF  = 0;            // 8192*512*2  = 8388608 (bf16)
constexpr size_t PWS_OFF  = 8388608;      // 512*16*256*4 = 8388608 (f32 P panels)
constexpr size_t PART_OFF = 16777216;     // 2048*4

typedef short bf16x8 __attribute__((ext_vector_type(8)));
typedef float f32x4  __attribute__((ext_vector_type(4)));

// round-to-nearest-even f32 -> bf16 bits
__device__ __forceinline__ short f2bf(float f) {
    unsigned u = __builtin_bit_cast(unsigned, f);
    unsigned r = (u + 0x7FFFu + ((u >> 16) & 1u)) >> 16;
    return (short)r;
}

// async global->LDS, 16B per lane; dest = uniform base + lane*16 (HW rule)
typedef __attribute__((address_space(3))) char lds_char;
typedef const __attribute__((address_space(1))) char g_char;
__device__ __forceinline__ void glds16(const void* g, void* l) {
    __builtin_amdgcn_global_load_lds((g_char*)g, (lds_char*)l, 16, 0, 0);
}

// ---------------------------------------------------------------------------
// K1: row-normalize fp32 -> bf16. One wave per row. 2048 blocks x 256.
__global__ __launch_bounds__(256) void k_normalize(const float* __restrict__ in,
                                                   short* __restrict__ out) {
    const int wid  = threadIdx.x >> 6;
    const int lane = threadIdx.x & 63;
    const int r    = blockIdx.x * 4 + wid;
    const float4* src = (const float4*)(in + (size_t)r * D);
    float4 x0 = src[2 * lane];
    float4 x1 = src[2 * lane + 1];
    float ss = x0.x*x0.x + x0.y*x0.y + x0.z*x0.z + x0.w*x0.w
             + x1.x*x1.x + x1.y*x1.y + x1.z*x1.z + x1.w*x1.w;
    #pragma unroll
    for (int o = 32; o > 0; o >>= 1) ss += __shfl_xor(ss, o, 64);
    const float inv = rsqrtf(ss);
    bf16x8 v;
    v[0] = f2bf(x0.x * inv); v[1] = f2bf(x0.y * inv);
    v[2] = f2bf(x0.z * inv); v[3] = f2bf(x0.w * inv);
    v[4] = f2bf(x1.x * inv); v[5] = f2bf(x1.y * inv);
    v[6] = f2bf(x1.z * inv); v[7] = f2bf(x1.w * inv);
    ((bf16x8*)(out + (size_t)r * D))[lane] = v;
}

// ---------------------------------------------------------------------------
// K2: gram panels. 512 blocks x 256 thr (4 waves), 2 independent blocks/CU.
// (unchanged from round 11)
__global__ __launch_bounds__(256, 2) void k_gram(const short* __restrict__ nrm,
                                                 float* __restrict__ pws) {
    __shared__ __align__(16) char smem[49152];    // 3 bufs x 16 KB

    const int p     = blockIdx.x;
    const int slot  = p >> 3;
    const int b     = (p & 7) * 4 + (slot & 3);   // XCD-bijective: 4 batches/XCD
    const int rem   = slot >> 2;                  // 0..15
    const int chunk = rem & 7;
    const int half  = rem >> 3;
    const int w     = threadIdx.x >> 6;
    const int lane  = threadIdx.x & 63;
    const int fr    = lane & 15;
    const int kg    = lane >> 4;

    const short* base = nrm + (size_t)b * 256 * D;
    const int Arow0 = half * 128 + chunk * 16;
    const short* gA = base + (size_t)(Arow0 + fr) * D + 8 * kg;
    const int brow0 = w * 64;                     // this wave's 64 B-rows

    auto stageB = [&](int ks, int bi) {
        #pragma unroll
        for (int t = 0; t < 4; t++) {
            const int sl  = t * 64 + lane;        // 16B chunk slot (0..255)
            const int row = sl >> 2;              // 0..63
            const int pp  = sl & 3;               // stored position
            const int gch = pp ^ (row & 3);       // pre-swizzled source chunk
            const short* src = base + (size_t)(brow0 + row) * D + ks * 32 + gch * 8;
            glds16(src, &smem[bi * 16384 + w * 4096 + t * 1024]); // +lane*16
        }
    };

    f32x4 acc0 = {0.f,0.f,0.f,0.f}, acc1 = {0.f,0.f,0.f,0.f};
    f32x4 acc2 = {0.f,0.f,0.f,0.f}, acc3 = {0.f,0.f,0.f,0.f};
    bf16x8 aA[3];                                 // rotating A buffers

    aA[0] = *(const bf16x8*)(gA + 0);
    stageB(0, 0);
    aA[1] = *(const bf16x8*)(gA + 32);
    stageB(1, 1);
    asm volatile("s_waitcnt vmcnt(5)" ::: "memory");
    __builtin_amdgcn_sched_barrier(0);

    const int pb = (kg ^ (fr & 3)) * 16;          // swizzled read position
    #pragma unroll
    for (int s = 0; s < 16; s++) {
        if (s < 14) {
            aA[(s + 2) % 3] = *(const bf16x8*)(gA + (s + 2) * 32);
            stageB(s + 2, (s + 2) % 3);
        }
        const int bo = (s % 3) * 16384 + w * 4096;
        bf16x8 b0 = *(const bf16x8*)&smem[bo + ( 0 + fr) * 64 + pb];
        bf16x8 b1 = *(const bf16x8*)&smem[bo + (16 + fr) * 64 + pb];
        bf16x8 b2 = *(const bf16x8*)&smem[bo + (32 + fr) * 64 + pb];
        bf16x8 b3 = *(const bf16x8*)&smem[bo + (48 + fr) * 64 + pb];
        acc0 = __builtin_amdgcn_mfma_f32_16x16x32_bf16(aA[s % 3], b0, acc0, 0, 0, 0);
        acc1 = __builtin_amdgcn_mfma_f32_16x16x32_bf16(aA[s % 3], b1, acc1, 0, 0, 0);
        acc2 = __builtin_amdgcn_mfma_f32_16x16x32_bf16(aA[s % 3], b2, acc2, 0, 0, 0);
        acc3 = __builtin_amdgcn_mfma_f32_16x16x32_bf16(aA[s % 3], b3, acc3, 0, 0, 0);
        if (s < 14)      { asm volatile("s_waitcnt vmcnt(5)" ::: "memory"); }
        else if (s == 14){ asm volatile("s_waitcnt vmcnt(0)" ::: "memory"); }
        __builtin_amdgcn_sched_barrier(0);
    }

    // C/D layout (m89-verified): lane l, reg q -> row kg*4+q, col fr
    float* Pb = pws + (size_t)p * 4096;
    #pragma unroll
    for (int q = 0; q < 4; q++) {
        const int r = kg * 4 + q;
        Pb[r * 256 + w * 64 +  0 + fr] = acc0[q];
        Pb[r * 256 + w * 64 + 16 + fr] = acc1[q];
        Pb[r * 256 + w * 64 + 32 + fr] = acc2[q];
        Pb[r * 256 + w * 64 + 48 + fr] = acc3[q];
    }
}

// ---------------------------------------------------------------------------
// K3: loss at full occupancy. 2048 blocks x 256 thr, one wave per P-row.
// IDENTICAL to round 11 EXCEPT: no counter / threadfence / atomic tail
// (single-variable experiment: R11's 49us is hypothesized to be 2048
// serialized same-address device atomics, Guideline 12).
__global__ __launch_bounds__(256) void k_loss(const float* __restrict__ pws,
                                              float* __restrict__ part) {
    __shared__ float sc[4][260];
    __shared__ float red[4];

    const int w    = threadIdx.x >> 6;
    const int lane = threadIdx.x & 63;
    const int rg   = blockIdx.x * 4 + w;          // 0..8191
    const int blk  = rg >> 4;                     // gram block id
    const int i    = rg & 15;
    const int half = ((blk >> 3) >> 2) >> 3;      // slot=blk>>3, rem=slot>>2, half=rem>>3
    const int pd_off = half ? 128 : 0;
    const int pn_off = 128 - pd_off;

    const float* Pr = pws + (size_t)blk * 4096 + i * 256;
    const float g0 = Pr[pd_off + lane];
    const float g1 = Pr[pd_off + lane + 64];
    float v0 = Pr[pn_off + lane];
    float v1 = Pr[pn_off + lane + 64];

    // bitonic sort ascending (2 elems/lane)
    #pragma unroll
    for (int kk = 2; kk <= 128; kk <<= 1) {
        if (kk == 128) {
            const float lo = fminf(v0, v1);
            const float hi = fmaxf(v0, v1);
            v0 = lo; v1 = hi;
        }
        #pragma unroll
        for (int j = (kk == 128 ? 32 : (kk >> 1)); j >= 1; j >>= 1) {
            const float p0 = __shfl_xor(v0, j, 64);
            const float p1 = __shfl_xor(v1, j, 64);
            const bool up0 = (lane & kk) == 0;
            const bool up1 = ((lane + 64) & kk) == 0;
            const bool lower = (lane & j) == 0;
            v0 = (up0 == lower) ? fminf(v0, p0) : fmaxf(v0, p0);
            v1 = (up1 == lower) ? fminf(v1, p1) : fmaxf(v1, p1);
        }
    }

    // inclusive prefix scans of the two halves
    float inc0 = v0, inc1 = v1;
    #pragma unroll
    for (int o = 1; o < 64; o <<= 1) {
        const float t0 = __shfl_up(inc0, o, 64);
        const float t1 = __shfl_up(inc1, o, 64);
        if (lane >= o) { inc0 += t0; inc1 += t1; }
    }
    const float tot0  = __shfl(inc0, 63, 64);
    const float total = tot0 + __shfl(inc1, 63, 64);

    // write sorted s[0:128] and exclusive prefix pre[0:129] to wave scratch
    float* prow = sc[w];
    prow[lane]            = v0;
    prow[64 + lane]       = v1;
    prow[130 + 1 + lane]  = inc0;
    prow[130 + 65 + lane] = tot0 + inc1;
    if (lane == 0) prow[130] = 0.f;

    // per-j: rank via guarded binary search, closed-form num/den
    float wacc = 0.f;
    #pragma unroll
    for (int h = 0; h < 2; h++) {
        const float g   = h ? g1 : g0;
        const float tau = g - 0.5f * ALPHA;       // v>0 <=> h_k > tau
        const float a   = ALPHA - 2.f * g;
        int pos = 0;
        #pragma unroll
        for (int st = 128; st > 0; st >>= 1) {
            const int nidx = pos + st;
            const float sv = prow[nidx - 1];
            pos = ((nidx <= 128) && (sv <= tau)) ? nidx : pos;
        }
        const float cnt = (float)(128 - pos);
        const float pre = prow[130 + pos];
        const float num = cnt * a + 2.f * (total - pre);
        wacc += num / (cnt + EPS);
    }

    #pragma unroll
    for (int o = 32; o > 0; o >>= 1) wacc += __shfl_xor(wacc, o, 64);
    if (lane == 0) red[w] = wacc;
    __syncthreads();
    if (threadIdx.x == 0)
        part[blockIdx.x] = red[0] + red[1] + red[2] + red[3];
}

// ---------------------------------------------------------------------------
// K4: final reduction of 2048 partials -> scalar loss. 1 block x 512.
__global__ __launch_bounds__(512) void k_reduce(const float* __restrict__ part,
                                                float* __restrict__ out) {
    __shared__ float red[8];
    const int w    = threadIdx.x >> 6;
    const int lane = threadIdx.x & 63;
    float s = part[threadIdx.x] + part[threadIdx.x + 512]
            + part[threadIdx.x + 1024] + part[threadIdx.x + 1536];
    #pragma unroll
    for (int o = 32; o > 0; o >>= 1) s += __shfl_xor(s, o, 64);
    if (lane == 0) red[w] = s;
    __syncthreads();
    if (threadIdx.x == 0) {
        float t = 0.f;
        #pragma unroll
        for (int i = 0; i < 8; i++) t += red[i];
        out[0] = t * INV_CNT;
    }
}

// ---------------------------------------------------------------------------
extern "C" void kernel_launch(void* const* d_in, const int* in_sizes, int n_in,
                              void* d_out, int out_size, void* d_ws, size_t ws_size,
                              hipStream_t stream) {
    const float* latent = (const float*)d_in[0];
    float* out  = (float*)d_out;
    char*  wsb  = (char*)d_ws;
    short* nrm  = (short*)(wsb + NRM_OFF);
    float* pws  = (float*)(wsb + PWS_OFF);
    float* part = (float*)(wsb + PART_OFF);

    hipLaunchKernelGGL(k_normalize, dim3(2048), dim3(256), 0, stream, latent, nrm);
    hipLaunchKernelGGL(k_gram,      dim3(512),  dim3(256), 0, stream, nrm, pws);
    hipLaunchKernelGGL(k_loss,      dim3(2048), dim3(256), 0, stream, pws, part);
    hipLaunchKernelGGL(k_reduce,    dim3(1),    dim3(512), 0, stream, part, out);
}

// Round 13
// 35.148 us; speedup vs baseline: 2.2090x; 1.0925x over previous
//
#include <hip/hip_runtime.h>
#include <hip/hip_bf16.h>

// Problem constants
constexpr int   D      = 512;
constexpr float ALPHA  = 1.0f;
constexpr float EPS    = 1e-9f;
constexpr float INV_CNT = 1.0f / (32.0f * 128.0f * 128.0f);  // 1/524288

// ws layout (bytes)
constexpr size_t NRM_OFF  = 0;            // 8192*512*2  = 8388608 (bf16, k-major)
constexpr size_t PWS_OFF  = 8388608;      // 512*16*256*4 = 8388608 (f32 P panels)
constexpr size_t PART_OFF = 16777216;     // 2048*4

typedef short bf16x8 __attribute__((ext_vector_type(8)));
typedef float f32x4  __attribute__((ext_vector_type(4)));

// round-to-nearest-even f32 -> bf16 bits
__device__ __forceinline__ short f2bf(float f) {
    unsigned u = __builtin_bit_cast(unsigned, f);
    unsigned r = (u + 0x7FFFu + ((u >> 16) & 1u)) >> 16;
    return (short)r;
}

// async global->LDS, 16B per lane; dest = wave-uniform base + lane*16 (HW rule)
typedef __attribute__((address_space(3))) char lds_char;
typedef const __attribute__((address_space(1))) char g_char;
__device__ __forceinline__ void glds16(const void* g, void* l) {
    __builtin_amdgcn_global_load_lds((g_char*)g, (lds_char*)l, 16, 0, 0);
}

// nrm2 layout (k-major, slot-rotated):
//   byte(b, ks, row, slot) = ((b*16 + ks)*256 + row)*64 + slot*16
// slot holds k-chunk (slot - (row>>1)) & 3  (rotation makes the gram
// fragment ds_read conflict-free: classes (row&1, slot) cover all 8
// mod-128 bank classes exactly 2x per 16-lane phase).

// ---------------------------------------------------------------------------
// K1: row-normalize fp32 -> bf16, writing the k-major rotated layout.
// One wave per row. 2048 blocks x 256.
__global__ __launch_bounds__(256) void k_normalize(const float* __restrict__ in,
                                                   short* __restrict__ nrm2) {
    const int wid  = threadIdx.x >> 6;
    const int lane = threadIdx.x & 63;
    const int r    = blockIdx.x * 4 + wid;        // global row 0..8191
    const int b    = r >> 8;
    const int row  = r & 255;
    const float4* src = (const float4*)(in + (size_t)r * D);
    float4 x0 = src[2 * lane];
    float4 x1 = src[2 * lane + 1];
    float ss = x0.x*x0.x + x0.y*x0.y + x0.z*x0.z + x0.w*x0.w
             + x1.x*x1.x + x1.y*x1.y + x1.z*x1.z + x1.w*x1.w;
    #pragma unroll
    for (int o = 32; o > 0; o >>= 1) ss += __shfl_xor(ss, o, 64);
    const float inv = rsqrtf(ss);
    bf16x8 v;                                     // elems 8*lane .. 8*lane+7
    v[0] = f2bf(x0.x * inv); v[1] = f2bf(x0.y * inv);
    v[2] = f2bf(x0.z * inv); v[3] = f2bf(x0.w * inv);
    v[4] = f2bf(x1.x * inv); v[5] = f2bf(x1.y * inv);
    v[6] = f2bf(x1.z * inv); v[7] = f2bf(x1.w * inv);
    const int ks   = lane >> 2;                   // k-slice 0..15
    const int slot = ((lane & 3) + (row >> 1)) & 3;
    char* dst = (char*)nrm2 + ((((size_t)b * 16 + ks) * 256 + row) * 64 + slot * 16);
    *(bf16x8*)dst = v;
}

// ---------------------------------------------------------------------------
// K2: gram panels. 512 blocks x 512 thr (8 waves), __launch_bounds__(512,4)
// -> 2 blocks/CU = 4 waves/SIMD (R12 ran 2/SIMD; latency-bound).
// Block = (b, chunk, half): A = 16 rows, B = all 256 batch rows.
// Wave w owns B-cols [w*32,+32): per step 1 A-load + 2 CONTIGUOUS 1KB glds
// (k-major layout; no row gather) + 2 conflict-free ds_read_b128 + 2 MFMA.
// Triple buffer, distance-2, vmcnt(3) steady (3 VMEM ops/step).
// P panel written f32 to ws: pws[blk][16][256] (same layout as R12).
__global__ __launch_bounds__(512, 4) void k_gram(const short* __restrict__ nrm2,
                                                 float* __restrict__ pws) {
    __shared__ __align__(16) char smem[49152];    // 3 bufs x 16 KB

    const int p     = blockIdx.x;
    const int slot  = p >> 3;
    const int b     = (p & 7) * 4 + (slot & 3);   // XCD-bijective: 4 batches/XCD
    const int rem   = slot >> 2;                  // 0..15
    const int chunk = rem & 7;
    const int half  = rem >> 3;
    const int w     = threadIdx.x >> 6;           // 0..7
    const int lane  = threadIdx.x & 63;
    const int fr    = lane & 15;
    const int kg    = lane >> 4;

    const char* batchbase = (const char*)nrm2 + (size_t)b * 16 * 256 * 64;

    // A: row Arow, chunk kg lives at rotated slot (kg + (Arow>>1))&3
    const int Arow  = half * 128 + chunk * 16 + fr;
    const int aslot = (kg + (Arow >> 1)) & 3;
    const char* gA  = batchbase + Arow * 64 + aslot * 16;   // + ks*16384 per step

    // B stage: wave w's 32 rows = 2 KB contiguous within the k-slice
    const char* gBl = batchbase + w * 2048 + lane * 16;     // + ks*16384 per step
    auto stageB = [&](int ks, int bi) {
        const char* s = gBl + (size_t)ks * 16384;
        glds16(s,        &smem[bi * 16384 + w * 2048]);
        glds16(s + 1024, &smem[bi * 16384 + w * 2048 + 1024]);
    };

    f32x4 acc0 = {0.f,0.f,0.f,0.f}, acc1 = {0.f,0.f,0.f,0.f};
    bf16x8 aA[3];                                 // rotating A buffers

    // prologue: [A0,B0x2, A1,B1x2] = 6 ops; wait until slice-0 group done
    aA[0] = *(const bf16x8*)(gA);
    stageB(0, 0);
    aA[1] = *(const bf16x8*)(gA + 16384);
    stageB(1, 1);
    asm volatile("s_waitcnt vmcnt(3)" ::: "memory");
    __builtin_amdgcn_sched_barrier(0);

    // fragment read: local row r' = g*16+fr, slot sigma = (kg + (fr>>1))&3
    // (w,g terms vanish mod 4) -> conflict-free (2-way, free)
    const int sigma = (kg + (fr >> 1)) & 3;
    const int ro0 = fr * 64 + sigma * 16;
    const int ro1 = (16 + fr) * 64 + sigma * 16;

    #pragma unroll
    for (int s = 0; s < 16; s++) {
        if (s < 14) {
            aA[(s + 2) % 3] = *(const bf16x8*)(gA + (size_t)(s + 2) * 16384);
            stageB(s + 2, (s + 2) % 3);
        }
        const int bo = (s % 3) * 16384 + w * 2048;
        bf16x8 b0 = *(const bf16x8*)&smem[bo + ro0];
        bf16x8 b1 = *(const bf16x8*)&smem[bo + ro1];
        acc0 = __builtin_amdgcn_mfma_f32_16x16x32_bf16(aA[s % 3], b0, acc0, 0, 0, 0);
        acc1 = __builtin_amdgcn_mfma_f32_16x16x32_bf16(aA[s % 3], b1, acc1, 0, 0, 0);
        if (s < 14)      { asm volatile("s_waitcnt vmcnt(3)" ::: "memory"); }
        else if (s == 14){ asm volatile("s_waitcnt vmcnt(0)" ::: "memory"); }
        __builtin_amdgcn_sched_barrier(0);
    }

    // C/D layout (m89-verified): lane l, reg q -> row kg*4+q, col fr
    float* Pb = pws + (size_t)p * 4096;
    #pragma unroll
    for (int q = 0; q < 4; q++) {
        const int r = kg * 4 + q;
        Pb[r * 256 + w * 32 +  0 + fr] = acc0[q];
        Pb[r * 256 + w * 32 + 16 + fr] = acc1[q];
    }
}

// ---------------------------------------------------------------------------
// K3: loss at full occupancy. 2048 blocks x 256 thr, one wave per P-row.
// (byte-identical to round 12, which passed with absmax 0)
__global__ __launch_bounds__(256) void k_loss(const float* __restrict__ pws,
                                              float* __restrict__ part) {
    __shared__ float sc[4][260];
    __shared__ float red[4];

    const int w    = threadIdx.x >> 6;
    const int lane = threadIdx.x & 63;
    const int rg   = blockIdx.x * 4 + w;          // 0..8191
    const int blk  = rg >> 4;                     // gram block id
    const int i    = rg & 15;
    const int half = ((blk >> 3) >> 2) >> 3;
    const int pd_off = half ? 128 : 0;
    const int pn_off = 128 - pd_off;

    const float* Pr = pws + (size_t)blk * 4096 + i * 256;
    const float g0 = Pr[pd_off + lane];
    const float g1 = Pr[pd_off + lane + 64];
    float v0 = Pr[pn_off + lane];
    float v1 = Pr[pn_off + lane + 64];

    // bitonic sort ascending (2 elems/lane)
    #pragma unroll
    for (int kk = 2; kk <= 128; kk <<= 1) {
        if (kk == 128) {
            const float lo = fminf(v0, v1);
            const float hi = fmaxf(v0, v1);
            v0 = lo; v1 = hi;
        }
        #pragma unroll
        for (int j = (kk == 128 ? 32 : (kk >> 1)); j >= 1; j >>= 1) {
            const float p0 = __shfl_xor(v0, j, 64);
            const float p1 = __shfl_xor(v1, j, 64);
            const bool up0 = (lane & kk) == 0;
            const bool up1 = ((lane + 64) & kk) == 0;
            const bool lower = (lane & j) == 0;
            v0 = (up0 == lower) ? fminf(v0, p0) : fmaxf(v0, p0);
            v1 = (up1 == lower) ? fminf(v1, p1) : fmaxf(v1, p1);
        }
    }

    // inclusive prefix scans of the two halves
    float inc0 = v0, inc1 = v1;
    #pragma unroll
    for (int o = 1; o < 64; o <<= 1) {
        const float t0 = __shfl_up(inc0, o, 64);
        const float t1 = __shfl_up(inc1, o, 64);
        if (lane >= o) { inc0 += t0; inc1 += t1; }
    }
    const float tot0  = __shfl(inc0, 63, 64);
    const float total = tot0 + __shfl(inc1, 63, 64);

    // write sorted s[0:128] and exclusive prefix pre[0:129] to wave scratch
    float* prow = sc[w];
    prow[lane]            = v0;
    prow[64 + lane]       = v1;
    prow[130 + 1 + lane]  = inc0;
    prow[130 + 65 + lane] = tot0 + inc1;
    if (lane == 0) prow[130] = 0.f;

    // per-j: rank via guarded binary search, closed-form num/den
    float wacc = 0.f;
    #pragma unroll
    for (int h = 0; h < 2; h++) {
        const float g   = h ? g1 : g0;
        const float tau = g - 0.5f * ALPHA;       // v>0 <=> h_k > tau
        const float a   = ALPHA - 2.f * g;
        int pos = 0;
        #pragma unroll
        for (int st = 128; st > 0; st >>= 1) {
            const int nidx = pos + st;
            const float sv = prow[nidx - 1];
            pos = ((nidx <= 128) && (sv <= tau)) ? nidx : pos;
        }
        const float cnt = (float)(128 - pos);
        const float pre = prow[130 + pos];
        const float num = cnt * a + 2.f * (total - pre);
        wacc += num / (cnt + EPS);
    }

    #pragma unroll
    for (int o = 32; o > 0; o >>= 1) wacc += __shfl_xor(wacc, o, 64);
    if (lane == 0) red[w] = wacc;
    __syncthreads();
    if (threadIdx.x == 0)
        part[blockIdx.x] = red[0] + red[1] + red[2] + red[3];
}

// ---------------------------------------------------------------------------
// K4: final reduction of 2048 partials -> scalar loss. 1 block x 512.
__global__ __launch_bounds__(512) void k_reduce(const float* __restrict__ part,
                                                float* __restrict__ out) {
    __shared__ float red[8];
    const int w    = threadIdx.x >> 6;
    const int lane = threadIdx.x & 63;
    float s = part[threadIdx.x] + part[threadIdx.x + 512]
            + part[threadIdx.x + 1024] + part[threadIdx.x + 1536];
    #pragma unroll
    for (int o = 32; o > 0; o >>= 1) s += __shfl_xor(s, o, 64);
    if (lane == 0) red[w] = s;
    __syncthreads();
    if (threadIdx.x == 0) {
        float t = 0.f;
        #pragma unroll
        for (int i = 0; i < 8; i++) t += red[i];
        out[0] = t * INV_CNT;
    }
}

// ---------------------------------------------------------------------------
extern "C" void kernel_launch(void* const* d_in, const int* in_sizes, int n_in,
                              void* d_out, int out_size, void* d_ws, size_t ws_size,
                              hipStream_t stream) {
    const float* latent = (const float*)d_in[0];
    float* out  = (float*)d_out;
    char*  wsb  = (char*)d_ws;
    short* nrm2 = (short*)(wsb + NRM_OFF);
    float* pws  = (float*)(wsb + PWS_OFF);
    float* part = (float*)(wsb + PART_OFF);

    hipLaunchKernelGGL(k_normalize, dim3(2048), dim3(256), 0, stream, latent, nrm2);
    hipLaunchKernelGGL(k_gram,      dim3(512),  dim3(512), 0, stream, nrm2, pws);
    hipLaunchKernelGGL(k_loss,      dim3(2048), dim3(256), 0, stream, pws, part);
    hipLaunchKernelGGL(k_reduce,    dim3(1),    dim3(512), 0, stream, part, out);
}

// Round 14
// 32.483 us; speedup vs baseline: 2.3902x; 1.0820x over previous
//
#include <hip/hip_runtime.h>
#include <hip/hip_bf16.h>

// Problem constants
constexpr int   D      = 512;
constexpr float ALPHA  = 1.0f;
constexpr float EPS    = 1e-9f;
constexpr float INV_CNT = 1.0f / (32.0f * 128.0f * 128.0f);  // 1/524288

// ws layout (bytes)
constexpr size_t NRM_OFF  = 0;            // 8192*512*2 = 8388608 (bf16, k-major)
constexpr size_t PART_OFF = 8388608;      // 512*4

typedef short bf16x8 __attribute__((ext_vector_type(8)));
typedef float f32x4  __attribute__((ext_vector_type(4)));

// round-to-nearest-even f32 -> bf16 bits
__device__ __forceinline__ short f2bf(float f) {
    unsigned u = __builtin_bit_cast(unsigned, f);
    unsigned r = (u + 0x7FFFu + ((u >> 16) & 1u)) >> 16;
    return (short)r;
}

// async global->LDS, 16B per lane; dest = wave-uniform base + lane*16 (HW rule)
typedef __attribute__((address_space(3))) char lds_char;
typedef const __attribute__((address_space(1))) char g_char;
__device__ __forceinline__ void glds16(const void* g, void* l) {
    __builtin_amdgcn_global_load_lds((g_char*)g, (lds_char*)l, 16, 0, 0);
}

// nrm2 layout (k-major, slot-rotated), written by k_normalize (R13-verified):
//   byte(b, ks, row, slot) = ((b*16 + ks)*256 + row)*64 + slot*16
//   chunk c of row r stored at slot (c + (r>>1)) & 3

// ---------------------------------------------------------------------------
// K1: row-normalize fp32 -> bf16 into k-major rotated layout.
// (byte-identical to round 13, which passed with absmax 0)
__global__ __launch_bounds__(256) void k_normalize(const float* __restrict__ in,
                                                   short* __restrict__ nrm2) {
    const int wid  = threadIdx.x >> 6;
    const int lane = threadIdx.x & 63;
    const int r    = blockIdx.x * 4 + wid;        // global row 0..8191
    const int b    = r >> 8;
    const int row  = r & 255;
    const float4* src = (const float4*)(in + (size_t)r * D);
    float4 x0 = src[2 * lane];
    float4 x1 = src[2 * lane + 1];
    float ss = x0.x*x0.x + x0.y*x0.y + x0.z*x0.z + x0.w*x0.w
             + x1.x*x1.x + x1.y*x1.y + x1.z*x1.z + x1.w*x1.w;
    #pragma unroll
    for (int o = 32; o > 0; o >>= 1) ss += __shfl_xor(ss, o, 64);
    const float inv = rsqrtf(ss);
    bf16x8 v;                                     // elems 8*lane .. 8*lane+7
    v[0] = f2bf(x0.x * inv); v[1] = f2bf(x0.y * inv);
    v[2] = f2bf(x0.z * inv); v[3] = f2bf(x0.w * inv);
    v[4] = f2bf(x1.x * inv); v[5] = f2bf(x1.y * inv);
    v[6] = f2bf(x1.z * inv); v[7] = f2bf(x1.w * inv);
    const int ks   = lane >> 2;                   // k-slice 0..15
    const int slot = ((lane & 3) + (row >> 1)) & 3;
    char* dst = (char*)nrm2 + ((((size_t)b * 16 + ks) * 256 + row) * 64 + slot * 16);
    *(bf16x8*)dst = v;
}

// ---------------------------------------------------------------------------
// K2: FUSED gram+loss per 16-row panel. 512 blocks x 256 thr (4 waves),
// __launch_bounds__(256,4) -> 4 blocks/CU (LDS 32.8 KB), 16 waves/CU.
// Gram: block = (b, chunk, half); A = 16 rows, B = 256 rows; wave w owns
//   B-cols [w*64,+64): per step 1 A-load + 4 contiguous 1KB glds + 4
//   ds_read_b128 + 4 MFMA; LDS double-buffer, distance-1, vmcnt(5) steady.
//   (Double-buffer safe: step s's ds_reads complete before its MFMAs issue
//   -- compiler lgkmcnt -- which precede step s+1's glds in program order.)
// Loss: P(16x256) -> LDS overlay; 4 rows/wave; verified sort + prefix +
//   binary-search closed form (rounds 3-13, absmax 0 throughout).
// Gram blocks and loss-phase blocks co-schedule on a CU (disjoint pipes).
constexpr int PSTR = 260;

__global__ __launch_bounds__(256, 4) void k_fused(const short* __restrict__ nrm2,
                                                  float* __restrict__ part) {
    __shared__ __align__(16) char smem[32832];    // 2x16KB arena; P overlays; red @32768

    const int p     = blockIdx.x;
    const int slot  = p >> 3;
    const int b     = (p & 7) * 4 + (slot & 3);   // XCD-bijective: 4 batches/XCD
    const int rem   = slot >> 2;                  // 0..15
    const int chunk = rem & 7;
    const int half  = rem >> 3;
    const int w     = threadIdx.x >> 6;           // 0..3
    const int lane  = threadIdx.x & 63;
    const int fr    = lane & 15;
    const int kg    = lane >> 4;

    const char* batchbase = (const char*)nrm2 + (size_t)b * 16 * 256 * 64;

    // A: row Arow, chunk kg at rotated slot (kg + (Arow>>1))&3 = sigma
    const int Arow  = half * 128 + chunk * 16 + fr;
    const int sigma = (kg + (fr >> 1)) & 3;       // (half*64+chunk*8, w*32, j*8 vanish mod 4)
    const char* gA  = batchbase + Arow * 64 + sigma * 16;   // + ks*16384 per step

    // B stage: wave w's 64 rows = 4 KB contiguous within each k-slice
    const char* gBl = batchbase + w * 4096 + lane * 16;     // + ks*16384 per step
    auto stageB = [&](int ks, int bi) {
        const char* s = gBl + (size_t)ks * 16384;
        char* d = &smem[bi * 16384 + w * 4096];
        glds16(s,        d);
        glds16(s + 1024, d + 1024);
        glds16(s + 2048, d + 2048);
        glds16(s + 3072, d + 3072);
    };

    f32x4 acc0 = {0.f,0.f,0.f,0.f}, acc1 = {0.f,0.f,0.f,0.f};
    f32x4 acc2 = {0.f,0.f,0.f,0.f}, acc3 = {0.f,0.f,0.f,0.f};
    bf16x8 aA[2];

    // prologue: group 0 = [A0, B0 x4] (5 VMEM ops)
    aA[0] = *(const bf16x8*)(gA);
    stageB(0, 0);

    // fragment read offsets (sigma pattern, R13-verified uniform banking)
    const int ro0 = ( 0 + fr) * 64 + sigma * 16;
    const int ro1 = (16 + fr) * 64 + sigma * 16;
    const int ro2 = (32 + fr) * 64 + sigma * 16;
    const int ro3 = (48 + fr) * 64 + sigma * 16;

    #pragma unroll
    for (int s = 0; s < 16; s++) {
        if (s < 15) {
            aA[(s + 1) & 1] = *(const bf16x8*)(gA + (size_t)(s + 1) * 16384);
            stageB(s + 1, (s + 1) & 1);
            asm volatile("s_waitcnt vmcnt(5)" ::: "memory");   // group s done
        } else {
            asm volatile("s_waitcnt vmcnt(0)" ::: "memory");
        }
        __builtin_amdgcn_sched_barrier(0);
        const int bo = (s & 1) * 16384 + w * 4096;
        bf16x8 b0 = *(const bf16x8*)&smem[bo + ro0];
        bf16x8 b1 = *(const bf16x8*)&smem[bo + ro1];
        bf16x8 b2 = *(const bf16x8*)&smem[bo + ro2];
        bf16x8 b3 = *(const bf16x8*)&smem[bo + ro3];
        acc0 = __builtin_amdgcn_mfma_f32_16x16x32_bf16(aA[s & 1], b0, acc0, 0, 0, 0);
        acc1 = __builtin_amdgcn_mfma_f32_16x16x32_bf16(aA[s & 1], b1, acc1, 0, 0, 0);
        acc2 = __builtin_amdgcn_mfma_f32_16x16x32_bf16(aA[s & 1], b2, acc2, 0, 0, 0);
        acc3 = __builtin_amdgcn_mfma_f32_16x16x32_bf16(aA[s & 1], b3, acc3, 0, 0, 0);
    }

    __syncthreads();   // staging arena dead; P overlays it

    float* P   = (float*)smem;                    // 16 x PSTR f32 = 16640 B
    float* red = (float*)&smem[32768];

    // C/D layout (m89-verified): lane l, reg q -> row kg*4+q, col fr (+16j)
    {
        const int rw = kg * 4;
        const int cw = w * 64 + fr;
        #pragma unroll
        for (int q = 0; q < 4; q++) P[(rw + q) * PSTR + cw]      = acc0[q];
        #pragma unroll
        for (int q = 0; q < 4; q++) P[(rw + q) * PSTR + cw + 16] = acc1[q];
        #pragma unroll
        for (int q = 0; q < 4; q++) P[(rw + q) * PSTR + cw + 32] = acc2[q];
        #pragma unroll
        for (int q = 0; q < 4; q++) P[(rw + q) * PSTR + cw + 48] = acc3[q];
    }
    __syncthreads();

    // ---- Loss phase: 4 rows per wave, wave-private (verified rounds 3-13) --
    const int pd_off = half ? 128 : 0;
    const int pn_off = 128 - pd_off;
    float wacc = 0.f;
    #pragma unroll
    for (int rr = 0; rr < 4; rr++) {
        const int r = w * 4 + rr;
        float* prow = &P[r * PSTR];

        const float g0 = prow[pd_off + lane];
        const float g1 = prow[pd_off + lane + 64];
        float v0 = prow[pn_off + lane];
        float v1 = prow[pn_off + lane + 64];

        // bitonic sort ascending (2 elems/lane)
        #pragma unroll
        for (int kk = 2; kk <= 128; kk <<= 1) {
            if (kk == 128) {
                const float lo = fminf(v0, v1);
                const float hi = fmaxf(v0, v1);
                v0 = lo; v1 = hi;
            }
            #pragma unroll
            for (int j = (kk == 128 ? 32 : (kk >> 1)); j >= 1; j >>= 1) {
                const float p0 = __shfl_xor(v0, j, 64);
                const float p1 = __shfl_xor(v1, j, 64);
                const bool up0 = (lane & kk) == 0;
                const bool up1 = ((lane + 64) & kk) == 0;
                const bool lower = (lane & j) == 0;
                v0 = (up0 == lower) ? fminf(v0, p0) : fmaxf(v0, p0);
                v1 = (up1 == lower) ? fminf(v1, p1) : fmaxf(v1, p1);
            }
        }

        // inclusive prefix scans of the two halves
        float inc0 = v0, inc1 = v1;
        #pragma unroll
        for (int o = 1; o < 64; o <<= 1) {
            const float t0 = __shfl_up(inc0, o, 64);
            const float t1 = __shfl_up(inc1, o, 64);
            if (lane >= o) { inc0 += t0; inc1 += t1; }
        }
        const float tot0  = __shfl(inc0, 63, 64);
        const float total = tot0 + __shfl(inc1, 63, 64);

        // write sorted s[0:128] and exclusive prefix pre[0:129] in place
        prow[lane]            = v0;
        prow[64 + lane]       = v1;
        prow[130 + 1 + lane]  = inc0;
        prow[130 + 65 + lane] = tot0 + inc1;
        if (lane == 0) prow[130] = 0.f;

        // per-j: rank via guarded binary search, closed-form num/den
        #pragma unroll
        for (int h = 0; h < 2; h++) {
            const float g   = h ? g1 : g0;
            const float tau = g - 0.5f * ALPHA;   // v>0 <=> h_k > tau
            const float a   = ALPHA - 2.f * g;
            int pos = 0;
            #pragma unroll
            for (int st = 128; st > 0; st >>= 1) {
                const int nidx = pos + st;
                const float sv = prow[nidx - 1];
                pos = ((nidx <= 128) && (sv <= tau)) ? nidx : pos;
            }
            const float cnt = (float)(128 - pos);
            const float pre = prow[130 + pos];
            const float num = cnt * a + 2.f * (total - pre);
            wacc += num / (cnt + EPS);
        }
    }

    #pragma unroll
    for (int o = 32; o > 0; o >>= 1) wacc += __shfl_xor(wacc, o, 64);
    if (lane == 0) red[w] = wacc;
    __syncthreads();
    if (threadIdx.x == 0)
        part[p] = red[0] + red[1] + red[2] + red[3];
}

// ---------------------------------------------------------------------------
// K3: final reduction of 512 partials -> scalar loss. 1 block x 512.
__global__ __launch_bounds__(512) void k_reduce(const float* __restrict__ part,
                                                float* __restrict__ out) {
    __shared__ float red[8];
    const int w    = threadIdx.x >> 6;
    const int lane = threadIdx.x & 63;
    float s = part[threadIdx.x];
    #pragma unroll
    for (int o = 32; o > 0; o >>= 1) s += __shfl_xor(s, o, 64);
    if (lane == 0) red[w] = s;
    __syncthreads();
    if (threadIdx.x == 0) {
        float t = 0.f;
        #pragma unroll
        for (int i = 0; i < 8; i++) t += red[i];
        out[0] = t * INV_CNT;
    }
}

// ---------------------------------------------------------------------------
extern "C" void kernel_launch(void* const* d_in, const int* in_sizes, int n_in,
                              void* d_out, int out_size, void* d_ws, size_t ws_size,
                              hipStream_t stream) {
    const float* latent = (const float*)d_in[0];
    float* out  = (float*)d_out;
    char*  wsb  = (char*)d_ws;
    short* nrm2 = (short*)(wsb + NRM_OFF);
    float* part = (float*)(wsb + PART_OFF);

    hipLaunchKernelGGL(k_normalize, dim3(2048), dim3(256), 0, stream, latent, nrm2);
    hipLaunchKernelGGL(k_fused,     dim3(512),  dim3(256), 0, stream, nrm2, part);
    hipLaunchKernelGGL(k_reduce,    dim3(1),    dim3(512), 0, stream, part, out);
}